// Round 1
// 156.778 us; speedup vs baseline: 1.0306x; 1.0306x over previous
//
#include <hip/hip_runtime.h>

#define NEGV -10000.0f

typedef _Float16 f16x8 __attribute__((ext_vector_type(8)));
typedef _Float16 f16x2 __attribute__((ext_vector_type(2)));
typedef float floatx4 __attribute__((ext_vector_type(4)));

// key (0..319) -> source sequence row. keys 0..63 local to query block nblk,
// keys 64..319 are the 256 global positions {0,61,62,63}+64j.
__device__ __forceinline__ int src_row(int key, int nblk) {
    if (key < 64) return nblk * 64 + key;
    int g = key - 64;
    int p = g & 3;
    return (g >> 2) * 64 + (p ? (60 + p) : 0);
}

// Swapped-QK + key-permutation layout:
//   K image slot (t, n) holds logical key L(t,n) = 32*(t>>1) + 8*(n>>2) + 4*(t&1) + (n&3).
//   QK = mfma(K, Q) -> acc[t][r] at lane (quad,m) = S[L(t, 4*quad+r)][qrow m].
//   Then pf[kc][4h+r] = acc[2kc+h][r] is EXACTLY the PV A-fragment for keys
//   32kc + 8*quad + j  -- pure in-lane cvt, no LDS round-trip for P.
__global__ __launch_bounds__(256, 3)
void sparse_attn_kernel(const float* __restrict__ Q, const float* __restrict__ K,
                        const float* __restrict__ V, const float* __restrict__ M,
                        float* __restrict__ O)
{
    // XCD swizzle: 4 whole heads per XCD so the head's global K/V rows stay in L2.
    const int x    = blockIdx.x;
    const int bh   = (x & 7) * 4 + ((x >> 3) >> 6);   // 0..31
    const int nblk = (x >> 3) & 63;                   // query block in head
    const int b    = bh >> 4;

    const size_t hoff = (size_t)bh * (4096 * 64);
    const float* Qh = Q + hoff;
    const float* Kh = K + hoff;
    const float* Vh = V + hoff;
    float*       Oh = O + hoff;
    const float* Mb = M + (size_t)b * 4096;

    // 40960 B. Phase 1: K image (40 slabs x 1024 B, frag-linear).
    // Phase 2 (after B2): VT image, slab (kc*4 + t) holds V^T frag for
    // keys 32kc..+31 x dims 16t..+15, XOR-swizzled by (t<<4) f16 for 2-way writes.
    __shared__ _Float16 smem[20480];

    const int tid  = threadIdx.x;
    const int lane = tid & 63;
    const int wv   = tid >> 6;          // wave -> query rows wv*16..+15
    const int m    = lane & 15;
    const int quad = lane >> 4;
    const int cg   = tid & 15;          // V col granule (4 floats)
    const int pg   = tid >> 4;          // V key-pair sub-index (0..15)

    // ---- mask: 5 values per lane + all-ones fast-path ballot ----
    float mv2[5];
    unsigned long long bb = 0ull;
    #pragma unroll
    for (int s = 0; s < 5; ++s) {
        float mval = Mb[src_row(s * 64 + lane, nblk)];
        bb |= __ballot(mval == 0.0f);
        mv2[s] = (mval == 0.0f) ? NEGV : 0.0f;
    }

    // ---- Q fragments direct from global (fp16); B-operand of swapped QK ----
    const int qrow = nblk * 64 + wv * 16 + m;
    f16x8 qf[2];
    #pragma unroll
    for (int c = 0; c < 2; ++c) {
        const float* src = Qh + (size_t)qrow * 64 + c * 32 + quad * 8;
        float4 f0 = *(const float4*)src;
        float4 f1 = *(const float4*)(src + 4);
        qf[c][0] = (_Float16)f0.x; qf[c][1] = (_Float16)f0.y;
        qf[c][2] = (_Float16)f0.z; qf[c][3] = (_Float16)f0.w;
        qf[c][4] = (_Float16)f1.x; qf[c][5] = (_Float16)f1.y;
        qf[c][6] = (_Float16)f1.z; qf[c][7] = (_Float16)f1.w;
    }

    // ---- stage K in A-fragment layout with the key permutation ----
    #pragma unroll
    for (int it = 0; it < 10; ++it) {
        int S    = it * 256 + tid;                       // 16B slot id, 0..2559
        int t    = S >> 7;
        int n    = S & 15;
        int col0 = ((S >> 6) & 1) * 32 + ((S & 63) >> 4) * 8;
        int lkey = 32 * (t >> 1) + 8 * (n >> 2) + 4 * (t & 1) + (n & 3);
        const float* src = Kh + (size_t)src_row(lkey, nblk) * 64 + col0;
        float4 f0 = *(const float4*)src;
        float4 f1 = *(const float4*)(src + 4);
        f16x8 o;
        o[0] = (_Float16)f0.x; o[1] = (_Float16)f0.y;
        o[2] = (_Float16)f0.z; o[3] = (_Float16)f0.w;
        o[4] = (_Float16)f1.x; o[5] = (_Float16)f1.y;
        o[6] = (_Float16)f1.z; o[7] = (_Float16)f1.w;
        *(f16x8*)(&smem[S * 8]) = o;
    }

    // ---- prefetch V batch 0 (keys 0..159) into registers; lands during QK ----
    float4 v0a[5], v0b[5];
    #pragma unroll
    for (int it = 0; it < 5; ++it) {
        int l0 = 2 * (it * 16 + pg);
        v0a[it] = *(const float4*)(Vh + (size_t)src_row(l0,     nblk) * 64 + cg * 4);
        v0b[it] = *(const float4*)(Vh + (size_t)src_row(l0 + 1, nblk) * 64 + cg * 4);
    }

    __syncthreads();   // B1: K image complete

    // ---- swapped QK^T: 40 MFMA, D[key][qrow] ----
    floatx4 acc[20] = {};
    #pragma unroll
    for (int t = 0; t < 20; ++t) {
        #pragma unroll
        for (int c = 0; c < 2; ++c) {
            f16x8 kf = *(const f16x8*)(&smem[(t * 2 + c) * 512 + lane * 8]);
            acc[t] = __builtin_amdgcn_mfma_f32_16x16x32_f16(kf, qf[c], acc[t], 0, 0, 0);
        }
    }

    __syncthreads();   // B2: all QK reads of K image done -> VT may overwrite

    // ---- VT store helper (logical key pair l0, one 4-dim granule) ----
    auto vt_store = [&](int l0, const float4& f0, const float4& f1) {
        int kc2   = l0 >> 5;
        int q2    = (l0 & 31) >> 3;
        int j0    = l0 & 7;
        int td    = cg >> 2;
        int sw    = td << 4;
        int lbase = (kc2 * 4 + td) * 512 + q2 * 128 + (cg & 3) * 32 + j0;
        f16x2 pk0; pk0[0] = (_Float16)f0.x; pk0[1] = (_Float16)f1.x;
        *(f16x2*)(&smem[(lbase +  0) ^ sw]) = pk0;
        f16x2 pk1; pk1[0] = (_Float16)f0.y; pk1[1] = (_Float16)f1.y;
        *(f16x2*)(&smem[(lbase +  8) ^ sw]) = pk1;
        f16x2 pk2; pk2[0] = (_Float16)f0.z; pk2[1] = (_Float16)f1.z;
        *(f16x2*)(&smem[(lbase + 16) ^ sw]) = pk2;
        f16x2 pk3; pk3[0] = (_Float16)f0.w; pk3[1] = (_Float16)f1.w;
        *(f16x2*)(&smem[(lbase + 24) ^ sw]) = pk3;
    };

    // ---- VT batch 0 writes (regs already resident) ----
    #pragma unroll
    for (int it = 0; it < 5; ++it)
        vt_store(2 * (it * 16 + pg), v0a[it], v0b[it]);

    // ---- prefetch V batch 1 (keys 160..319); latency hidden under softmax ----
    float4 v1a[5], v1b[5];
    #pragma unroll
    for (int it = 0; it < 5; ++it) {
        int l0 = 2 * ((5 + it) * 16 + pg);
        v1a[it] = *(const float4*)(Vh + (size_t)src_row(l0,     nblk) * 64 + cg * 4);
        v1b[it] = *(const float4*)(Vh + (size_t)src_row(l0 + 1, nblk) * 64 + cg * 4);
    }

    // ---- mask slow path (only when any position masked out) ----
    if (bb != 0ull) {
        #pragma unroll
        for (int t = 0; t < 20; ++t) {
            int lb = 32 * ((t >> 1) & 1) + 4 * (t & 1) + 8 * quad;
            #pragma unroll
            for (int r = 0; r < 4; ++r)
                acc[t][r] += __shfl(mv2[t >> 2], lb + r, 64);
        }
    }

    // ---- softmax: lane holds one full q-row (80 keys); reduce over quads ----
    float rmax = -3e38f;
    #pragma unroll
    for (int t = 0; t < 20; ++t)
        #pragma unroll
        for (int r = 0; r < 4; ++r)
            rmax = fmaxf(rmax, acc[t][r]);
    rmax = fmaxf(rmax, __shfl_xor(rmax, 16, 64));
    rmax = fmaxf(rmax, __shfl_xor(rmax, 32, 64));
    float rsum = 0.f;
    #pragma unroll
    for (int t = 0; t < 20; ++t)
        #pragma unroll
        for (int r = 0; r < 4; ++r) {
            float e = __expf(acc[t][r] - rmax);
            acc[t][r] = e;                 // unnormalized; 1/sum at epilogue
            rsum += e;
        }
    rsum += __shfl_xor(rsum, 16, 64);
    rsum += __shfl_xor(rsum, 32, 64);
    float rinv = 1.0f / rsum;

    // ---- VT batch 1 writes ----
    #pragma unroll
    for (int it = 0; it < 5; ++it)
        vt_store(2 * ((5 + it) * 16 + pg), v1a[it], v1b[it]);

    // ---- P fragments: pure in-lane cvt thanks to the key permutation ----
    f16x8 pf[10];
    #pragma unroll
    for (int k2 = 0; k2 < 10; ++k2) {
        #pragma unroll
        for (int r = 0; r < 4; ++r) {
            pf[k2][r]     = (_Float16)acc[2 * k2][r];
            pf[k2][4 + r] = (_Float16)acc[2 * k2 + 1][r];
        }
    }

    __syncthreads();   // B3: VT image complete

    // ---- PV: 40 MFMA ----
    floatx4 oacc[4] = {};
    #pragma unroll
    for (int k2 = 0; k2 < 10; ++k2) {
        #pragma unroll
        for (int t = 0; t < 4; ++t) {
            f16x8 vf = *(const f16x8*)(&smem[(k2 * 4 + t) * 512 + ((lane * 8) ^ (t << 4))]);
            oacc[t] = __builtin_amdgcn_mfma_f32_16x16x32_f16(pf[k2], vf, oacc[t], 0, 0, 0);
        }
    }

    // ---- epilogue: apply 1/rowsum, store fp32 ----
    float rinvr[4];
    #pragma unroll
    for (int r = 0; r < 4; ++r)
        rinvr[r] = __shfl(rinv, quad * 4 + r, 64);
    #pragma unroll
    for (int t = 0; t < 4; ++t)
        #pragma unroll
        for (int r = 0; r < 4; ++r)
            Oh[(size_t)(nblk * 64 + wv * 16 + quad * 4 + r) * 64 + t * 16 + m] =
                oacc[t][r] * rinvr[r];
}

extern "C" void kernel_launch(void* const* d_in, const int* in_sizes, int n_in,
                              void* d_out, int out_size, void* d_ws, size_t ws_size,
                              hipStream_t stream) {
    const float* q    = (const float*)d_in[0];
    const float* k    = (const float*)d_in[1];
    const float* v    = (const float*)d_in[2];
    const float* mask = (const float*)d_in[3];
    float* out = (float*)d_out;
    (void)in_sizes; (void)n_in; (void)out_size; (void)d_ws; (void)ws_size;
    sparse_attn_kernel<<<2 * 16 * 64, 256, 0, stream>>>(q, k, v, mask, out);
}